// Round 1
// baseline (283.312 us; speedup 1.0000x reference)
//
#include <hip/hip_runtime.h>
#include <math.h>

#define B 2
#define T 512
#define C 512
#define H 64

// scale = C^-0.5 = 1/sqrt(512)
#define SCALE 0.044194173824159216f

static __device__ __forceinline__ float qnan() { return __builtin_nanf(""); }

// ---------------------------------------------------------------------------
// Kernel 1: sequential token scans -> prop_time[b][p], prop_pitch[b][p]
// prop_time: round(abs_t_at_last_time_token / 10) (NaN before first time tok)
// prop_pitch: pitch value at last note token, SHIFTED: prop[t] = ff[min(t+1,T-1)]
// ---------------------------------------------------------------------------
__global__ void scan_kernel(const int* __restrict__ tok,
                            float* __restrict__ prop_t,
                            float* __restrict__ prop_p) {
    int b = threadIdx.x;
    if (b >= B) return;
    const int* tb = tok + b * T;

    // time scan
    float cum = 0.0f;
    float cur = 0.0f;
    bool have = false;
    for (int p = 0; p < T; ++p) {
        int tk = tb[p];
        if (tk >= 288) {               // TIME_SHIFT_OFFSET
            cum += (float)(tk - 288);
            cur = cum + 1.0f;
            have = true;
        }
        prop_t[b * T + p] = have ? rintf(cur / 10.0f) : qnan();
    }

    // pitch scan (shifted by one)
    float ff = 0.0f;
    bool havef = false;
    for (int p = 0; p < T; ++p) {
        int tk = tb[p];
        float val = (float)((tk >= 128 ? tk - 128 : tk) + 1);  // NOTE_OFF_OFFSET
        if (tk < 256) {                // VELOCITY_OFFSET -> note token
            ff = val;
            havef = true;
        }
        if (p >= 1) prop_p[b * T + (p - 1)] = havef ? ff : qnan();
    }
    prop_p[b * T + (T - 1)] = havef ? ff : qnan();
}

// ---------------------------------------------------------------------------
// Kernel 2: q/k/v projections. One block per (b,t), 64 threads (one per h).
// x row staged in LDS; W loads coalesced across threads.
// ---------------------------------------------------------------------------
__global__ __launch_bounds__(64) void qkv_kernel(const float* __restrict__ x,
                                                 const float* __restrict__ Wq,
                                                 const float* __restrict__ Wk,
                                                 const float* __restrict__ Wv,
                                                 float* __restrict__ q,
                                                 float* __restrict__ k,
                                                 float* __restrict__ v) {
    int bt = blockIdx.x;
    int c = threadIdx.x;
    __shared__ float xs[C];
    const float* xrow = x + (size_t)bt * C;
    for (int i = c; i < C; i += 64) xs[i] = xrow[i];
    __syncthreads();

    float aq = 0.f, ak = 0.f, av = 0.f;
#pragma unroll 8
    for (int kk = 0; kk < C; ++kk) {
        float xv = xs[kk];
        aq = fmaf(xv, Wq[kk * H + c], aq);
        ak = fmaf(xv, Wk[kk * H + c], ak);
        av = fmaf(xv, Wv[kk * H + c], av);
    }
    size_t o = (size_t)bt * H + c;
    q[o] = aq;
    k[o] = ak;
    v[o] = av;
}

// ---------------------------------------------------------------------------
// Kernel 3: relative-embedding sums, fused into k' = scale*k + Rk, v' = v + Rv
// (in-place on k/v). One block per (b,j), 64 threads (one per h).
// ---------------------------------------------------------------------------
__global__ __launch_bounds__(64) void relsum_kernel(
    const float* __restrict__ prop_t, const float* __restrict__ prop_p,
    const float* __restrict__ Ek_pos, const float* __restrict__ Ev_pos,
    const float* __restrict__ Ek_time, const float* __restrict__ Ev_time,
    const float* __restrict__ Ek_pitch, const float* __restrict__ Ev_pitch,
    float* __restrict__ k, float* __restrict__ v) {
    int b = blockIdx.x >> 9;   // / T
    int j = blockIdx.x & 511;  // % T
    int c = threadIdx.x;

    __shared__ float pt[T];
    __shared__ float pp[T];
    for (int i = c; i < T; i += 64) {
        pt[i] = prop_t[b * T + i];
        pp[i] = prop_p[b * T + i];
    }
    __syncthreads();

    float pjt = pt[j];
    float pjp = pp[j];
    float aK = 0.f, aV = 0.f;

#pragma unroll 4
    for (int i = 0; i < T; ++i) {
        // position: pd[i,j] = clip(j-i, -25, 25) + 25
        int pd = min(max(j - i, -25), 25) + 25;
        aK += Ek_pos[pd * H + c];
        aV += Ev_pos[pd * H + c];

        // time: idx = clip(prop_t[j]-prop_t[i], -200, 200)+200, NaN->0
        float dt = pjt - pt[i];
        int ti;
        if (dt != dt) ti = 0;
        else ti = (int)fminf(fmaxf(dt, -200.f), 200.f) + 200;
        aK += Ek_time[ti * H + c];
        aV += Ev_time[ti * H + c];

        // pitch: idx = clip(prop_p[j]-prop_p[i], -128, 128)+128, NaN->0
        float dp = pjp - pp[i];
        int ni;
        if (dp != dp) ni = 0;
        else ni = (int)fminf(fmaxf(dp, -128.f), 128.f) + 128;
        aK += Ek_pitch[ni * H + c];
        aV += Ev_pitch[ni * H + c];
    }

    size_t o = (size_t)blockIdx.x * H + c;
    k[o] = SCALE * k[o] + aK;
    v[o] = v[o] + aV;
}

// ---------------------------------------------------------------------------
// Kernel 4: causal attention with fused k'/v'. One block (=1 wave, 64 thr) per
// (b,t). Scores via LDS-staged k' tiles (stride 65 -> conflict-free).
// ---------------------------------------------------------------------------
__global__ __launch_bounds__(64) void attn_kernel(const float* __restrict__ q,
                                                  const float* __restrict__ kp,
                                                  const float* __restrict__ vp,
                                                  float* __restrict__ out) {
    int b = blockIdx.x >> 9;
    int t = blockIdx.x & 511;
    int tid = threadIdx.x;

    __shared__ float qs[H];
    __shared__ float sc[T];
    __shared__ float ktile[64 * 65];

    qs[tid] = q[(size_t)blockIdx.x * H + tid];
    __syncthreads();

    int ns = t + 1;
    const float* kbase = kp + (size_t)b * T * H;
    const float* vbase = vp + (size_t)b * T * H;

    for (int s0 = 0; s0 < ns; s0 += 64) {
        int tile = min(64, ns - s0);
        for (int r = 0; r < tile; ++r)
            ktile[r * 65 + tid] = kbase[(size_t)(s0 + r) * H + tid];
        __syncthreads();
        if (tid < tile) {
            float d = 0.f;
#pragma unroll
            for (int c2 = 0; c2 < H; ++c2)
                d = fmaf(qs[c2], ktile[tid * 65 + c2], d);
            sc[s0 + tid] = d;
        }
        __syncthreads();
    }

    // softmax over sc[0..ns)
    float m = -INFINITY;
    for (int s = tid; s < ns; s += 64) m = fmaxf(m, sc[s]);
#pragma unroll
    for (int off = 32; off; off >>= 1) m = fmaxf(m, __shfl_down(m, off));
    m = __shfl(m, 0);

    float sum = 0.f;
    for (int s = tid; s < ns; s += 64) {
        float e = __expf(sc[s] - m);
        sc[s] = e;
        sum += e;
    }
#pragma unroll
    for (int off = 32; off; off >>= 1) sum += __shfl_down(sum, off);
    sum = __shfl(sum, 0);
    __syncthreads();

    float inv = 1.0f / sum;
    float acc = 0.f;
    for (int s = 0; s < ns; ++s)
        acc = fmaf(sc[s], vbase[(size_t)s * H + tid], acc);

    out[(size_t)blockIdx.x * H + tid] = acc * inv;
}

// ---------------------------------------------------------------------------
extern "C" void kernel_launch(void* const* d_in, const int* in_sizes, int n_in,
                              void* d_out, int out_size, void* d_ws, size_t ws_size,
                              hipStream_t stream) {
    const float* x        = (const float*)d_in[0];
    const int*   tok      = (const int*)d_in[1];
    const float* Wk       = (const float*)d_in[2];
    const float* Wq       = (const float*)d_in[3];
    const float* Wv       = (const float*)d_in[4];
    const float* Ek_pos   = (const float*)d_in[5];
    const float* Ev_pos   = (const float*)d_in[6];
    const float* Ek_time  = (const float*)d_in[7];
    const float* Ev_time  = (const float*)d_in[8];
    const float* Ek_pitch = (const float*)d_in[9];
    const float* Ev_pitch = (const float*)d_in[10];
    float* out = (float*)d_out;

    // workspace layout (floats)
    float* ws = (float*)d_ws;
    float* q      = ws;                       // B*T*H
    float* k      = q + B * T * H;            // B*T*H (becomes k')
    float* v      = k + B * T * H;            // B*T*H (becomes v')
    float* prop_t = v + B * T * H;            // B*T
    float* prop_p = prop_t + B * T;           // B*T

    scan_kernel<<<1, 64, 0, stream>>>(tok, prop_t, prop_p);
    qkv_kernel<<<B * T, 64, 0, stream>>>(x, Wq, Wk, Wv, q, k, v);
    relsum_kernel<<<B * T, 64, 0, stream>>>(prop_t, prop_p, Ek_pos, Ev_pos,
                                            Ek_time, Ev_time, Ek_pitch, Ev_pitch,
                                            k, v);
    attn_kernel<<<B * T, 64, 0, stream>>>(q, k, v, out);
}

// Round 2
// 191.647 us; speedup vs baseline: 1.4783x; 1.4783x over previous
//
#include <hip/hip_runtime.h>
#include <math.h>

#define B 2
#define T 512
#define C 512
#define H 64

// scale = C^-0.5 = 1/sqrt(512)
#define SCALE 0.044194173824159216f

static __device__ __forceinline__ float qnan() { return __builtin_nanf(""); }

// ---------------------------------------------------------------------------
// Kernel 1: parallel token scans -> prop_time[b][p], prop_pitch[b][p]
// One wave (64 lanes) per batch; 8 positions per lane.
//   time  = prefix-sum of max(tok-288,0) (+1, /10, rint) gated by prefix-OR
//   pitch = copy-last-valid scan of note values, shifted left by one
// ---------------------------------------------------------------------------
__global__ __launch_bounds__(64) void scan_kernel(const int* __restrict__ tok,
                                                  float* __restrict__ prop_t,
                                                  float* __restrict__ prop_p) {
    int b = blockIdx.x;
    int lane = threadIdx.x;
    const int* tb = tok + b * T;

    __shared__ int tks[T];
    __shared__ float ff[T];
    for (int i = lane; i < T; i += 64) tks[i] = tb[i];
    __syncthreads();

    const int p0 = lane * 8;
    unsigned long long lowmask = lane ? ((1ull << lane) - 1ull) : 0ull;

    // ---- time scan ----
    float lsum[8];
    bool lflag[8];
    {
        float s = 0.f;
        bool f = false;
#pragma unroll
        for (int i = 0; i < 8; ++i) {
            int tk = tks[p0 + i];
            if (tk >= 288) { s += (float)(tk - 288); f = true; }
            lsum[i] = s;
            lflag[i] = f;
        }
        // wave inclusive prefix sum of lane totals -> exclusive
        float inc = s;
#pragma unroll
        for (int off = 1; off < 64; off <<= 1) {
            float o = __shfl_up(inc, off);
            if (lane >= off) inc += o;
        }
        float ex = inc - s;
        unsigned long long fmask = __ballot(f);
        bool exf = (fmask & lowmask) != 0ull;
#pragma unroll
        for (int i = 0; i < 8; ++i) {
            bool have = exf | lflag[i];
            float cum = ex + lsum[i];
            prop_t[b * T + p0 + i] = have ? rintf((cum + 1.0f) / 10.0f) : qnan();
        }
    }

    // ---- pitch scan (copy-last-valid, then shift left by one) ----
    {
        float lval[8];
        bool lvalid[8];
        float cv = 0.f;
        bool cvd = false;
#pragma unroll
        for (int i = 0; i < 8; ++i) {
            int tk = tks[p0 + i];
            if (tk < 256) {  // note token
                cv = (float)((tk >= 128 ? tk - 128 : tk) + 1);
                cvd = true;
            }
            lval[i] = cv;
            lvalid[i] = cvd;
        }
        unsigned long long vmask = __ballot(cvd);
        unsigned long long lower = vmask & lowmask;
        bool exvd = lower != 0ull;
        int src = 63 - __clzll(lower | 1ull);  // highest set lane below me (valid iff exvd)
        float exv = __shfl(cv, src);
#pragma unroll
        for (int i = 0; i < 8; ++i) {
            bool hv = exvd | lvalid[i];
            float fv = lvalid[i] ? lval[i] : exv;
            ff[p0 + i] = hv ? fv : qnan();
        }
        __syncthreads();
        for (int i = lane; i < T; i += 64) {
            int nxt = min(i + 1, T - 1);
            prop_p[b * T + i] = ff[nxt];
        }
    }
}

// ---------------------------------------------------------------------------
// Kernel 2: q/k/v projections. One block per (b,t), 64 threads (one per h).
// ---------------------------------------------------------------------------
__global__ __launch_bounds__(64) void qkv_kernel(const float* __restrict__ x,
                                                 const float* __restrict__ Wq,
                                                 const float* __restrict__ Wk,
                                                 const float* __restrict__ Wv,
                                                 float* __restrict__ q,
                                                 float* __restrict__ k,
                                                 float* __restrict__ v) {
    int bt = blockIdx.x;
    int c = threadIdx.x;
    __shared__ float xs[C];
    const float* xrow = x + (size_t)bt * C;
    for (int i = c; i < C; i += 64) xs[i] = xrow[i];
    __syncthreads();

    float aq = 0.f, ak = 0.f, av = 0.f;
#pragma unroll 8
    for (int kk = 0; kk < C; ++kk) {
        float xv = xs[kk];
        aq = fmaf(xv, Wq[kk * H + c], aq);
        ak = fmaf(xv, Wk[kk * H + c], ak);
        av = fmaf(xv, Wv[kk * H + c], av);
    }
    size_t o = (size_t)bt * H + c;
    q[o] = aq;
    k[o] = ak;
    v[o] = av;
}

// ---------------------------------------------------------------------------
// Kernel 3: relative-embedding sums, fused into k' = scale*k + Rk, v' = v + Rv
// ---------------------------------------------------------------------------
__global__ __launch_bounds__(64) void relsum_kernel(
    const float* __restrict__ prop_t, const float* __restrict__ prop_p,
    const float* __restrict__ Ek_pos, const float* __restrict__ Ev_pos,
    const float* __restrict__ Ek_time, const float* __restrict__ Ev_time,
    const float* __restrict__ Ek_pitch, const float* __restrict__ Ev_pitch,
    float* __restrict__ k, float* __restrict__ v) {
    int b = blockIdx.x >> 9;   // / T
    int j = blockIdx.x & 511;  // % T
    int c = threadIdx.x;

    __shared__ float pt[T];
    __shared__ float pp[T];
    for (int i = c; i < T; i += 64) {
        pt[i] = prop_t[b * T + i];
        pp[i] = prop_p[b * T + i];
    }
    __syncthreads();

    float pjt = pt[j];
    float pjp = pp[j];
    float aK = 0.f, aV = 0.f;

#pragma unroll 4
    for (int i = 0; i < T; ++i) {
        int pd = min(max(j - i, -25), 25) + 25;
        aK += Ek_pos[pd * H + c];
        aV += Ev_pos[pd * H + c];

        float dt = pjt - pt[i];
        int ti;
        if (dt != dt) ti = 0;
        else ti = (int)fminf(fmaxf(dt, -200.f), 200.f) + 200;
        aK += Ek_time[ti * H + c];
        aV += Ev_time[ti * H + c];

        float dp = pjp - pp[i];
        int ni;
        if (dp != dp) ni = 0;
        else ni = (int)fminf(fmaxf(dp, -128.f), 128.f) + 128;
        aK += Ek_pitch[ni * H + c];
        aV += Ev_pitch[ni * H + c];
    }

    size_t o = (size_t)blockIdx.x * H + c;
    k[o] = SCALE * k[o] + aK;
    v[o] = v[o] + aV;
}

// ---------------------------------------------------------------------------
// Kernel 4: causal attention with fused k'/v'. One block (=1 wave) per (b,t).
// ---------------------------------------------------------------------------
__global__ __launch_bounds__(64) void attn_kernel(const float* __restrict__ q,
                                                  const float* __restrict__ kp,
                                                  const float* __restrict__ vp,
                                                  float* __restrict__ out) {
    int b = blockIdx.x >> 9;
    int t = blockIdx.x & 511;
    int tid = threadIdx.x;

    __shared__ float qs[H];
    __shared__ float sc[T];
    __shared__ float ktile[64 * 65];

    qs[tid] = q[(size_t)blockIdx.x * H + tid];
    __syncthreads();

    int ns = t + 1;
    const float* kbase = kp + (size_t)b * T * H;
    const float* vbase = vp + (size_t)b * T * H;

    for (int s0 = 0; s0 < ns; s0 += 64) {
        int tile = min(64, ns - s0);
        for (int r = 0; r < tile; ++r)
            ktile[r * 65 + tid] = kbase[(size_t)(s0 + r) * H + tid];
        __syncthreads();
        if (tid < tile) {
            float d = 0.f;
#pragma unroll
            for (int c2 = 0; c2 < H; ++c2)
                d = fmaf(qs[c2], ktile[tid * 65 + c2], d);
            sc[s0 + tid] = d;
        }
        __syncthreads();
    }

    float m = -INFINITY;
    for (int s = tid; s < ns; s += 64) m = fmaxf(m, sc[s]);
#pragma unroll
    for (int off = 32; off; off >>= 1) m = fmaxf(m, __shfl_down(m, off));
    m = __shfl(m, 0);

    float sum = 0.f;
    for (int s = tid; s < ns; s += 64) {
        float e = __expf(sc[s] - m);
        sc[s] = e;
        sum += e;
    }
#pragma unroll
    for (int off = 32; off; off >>= 1) sum += __shfl_down(sum, off);
    sum = __shfl(sum, 0);
    __syncthreads();

    float inv = 1.0f / sum;
    float acc = 0.f;
    for (int s = 0; s < ns; ++s)
        acc = fmaf(sc[s], vbase[(size_t)s * H + tid], acc);

    out[(size_t)blockIdx.x * H + tid] = acc * inv;
}

// ---------------------------------------------------------------------------
extern "C" void kernel_launch(void* const* d_in, const int* in_sizes, int n_in,
                              void* d_out, int out_size, void* d_ws, size_t ws_size,
                              hipStream_t stream) {
    const float* x        = (const float*)d_in[0];
    const int*   tok      = (const int*)d_in[1];
    const float* Wk       = (const float*)d_in[2];
    const float* Wq       = (const float*)d_in[3];
    const float* Wv       = (const float*)d_in[4];
    const float* Ek_pos   = (const float*)d_in[5];
    const float* Ev_pos   = (const float*)d_in[6];
    const float* Ek_time  = (const float*)d_in[7];
    const float* Ev_time  = (const float*)d_in[8];
    const float* Ek_pitch = (const float*)d_in[9];
    const float* Ev_pitch = (const float*)d_in[10];
    float* out = (float*)d_out;

    float* ws = (float*)d_ws;
    float* q      = ws;                       // B*T*H
    float* k      = q + B * T * H;            // B*T*H (becomes k')
    float* v      = k + B * T * H;            // B*T*H (becomes v')
    float* prop_t = v + B * T * H;            // B*T
    float* prop_p = prop_t + B * T;           // B*T

    scan_kernel<<<B, 64, 0, stream>>>(tok, prop_t, prop_p);
    qkv_kernel<<<B * T, 64, 0, stream>>>(x, Wq, Wk, Wv, q, k, v);
    relsum_kernel<<<B * T, 64, 0, stream>>>(prop_t, prop_p, Ek_pos, Ev_pos,
                                            Ek_time, Ev_time, Ek_pitch, Ev_pitch,
                                            k, v);
    attn_kernel<<<B * T, 64, 0, stream>>>(q, k, v, out);
}

// Round 3
// 156.355 us; speedup vs baseline: 1.8120x; 1.2257x over previous
//
#include <hip/hip_runtime.h>
#include <math.h>

#define B 2
#define T 512
#define C 512
#define H 64

// scale = C^-0.5 = 1/sqrt(512)
#define SCALE 0.044194173824159216f

static __device__ __forceinline__ float qnan() { return __builtin_nanf(""); }

// ---------------------------------------------------------------------------
// Kernel 1: parallel token scans (one wave per batch), unchanged from R1.
// ---------------------------------------------------------------------------
__global__ __launch_bounds__(64) void scan_kernel(const int* __restrict__ tok,
                                                  float* __restrict__ prop_t,
                                                  float* __restrict__ prop_p) {
    int b = blockIdx.x;
    int lane = threadIdx.x;
    const int* tb = tok + b * T;

    __shared__ int tks[T];
    __shared__ float ff[T];
    for (int i = lane; i < T; i += 64) tks[i] = tb[i];
    __syncthreads();

    const int p0 = lane * 8;
    unsigned long long lowmask = lane ? ((1ull << lane) - 1ull) : 0ull;

    // ---- time scan ----
    {
        float lsum[8];
        bool lflag[8];
        float s = 0.f;
        bool f = false;
#pragma unroll
        for (int i = 0; i < 8; ++i) {
            int tk = tks[p0 + i];
            if (tk >= 288) { s += (float)(tk - 288); f = true; }
            lsum[i] = s;
            lflag[i] = f;
        }
        float inc = s;
#pragma unroll
        for (int off = 1; off < 64; off <<= 1) {
            float o = __shfl_up(inc, off);
            if (lane >= off) inc += o;
        }
        float ex = inc - s;
        unsigned long long fmask = __ballot(f);
        bool exf = (fmask & lowmask) != 0ull;
#pragma unroll
        for (int i = 0; i < 8; ++i) {
            bool have = exf | lflag[i];
            float cum = ex + lsum[i];
            prop_t[b * T + p0 + i] = have ? rintf((cum + 1.0f) / 10.0f) : qnan();
        }
    }

    // ---- pitch scan (copy-last-valid, then shift left by one) ----
    {
        float lval[8];
        bool lvalid[8];
        float cv = 0.f;
        bool cvd = false;
#pragma unroll
        for (int i = 0; i < 8; ++i) {
            int tk = tks[p0 + i];
            if (tk < 256) {
                cv = (float)((tk >= 128 ? tk - 128 : tk) + 1);
                cvd = true;
            }
            lval[i] = cv;
            lvalid[i] = cvd;
        }
        unsigned long long vmask = __ballot(cvd);
        unsigned long long lower = vmask & lowmask;
        bool exvd = lower != 0ull;
        int src = 63 - __clzll(lower | 1ull);
        float exv = __shfl(cv, src);
#pragma unroll
        for (int i = 0; i < 8; ++i) {
            bool hv = exvd | lvalid[i];
            float fv = lvalid[i] ? lval[i] : exv;
            ff[p0 + i] = hv ? fv : qnan();
        }
        __syncthreads();
        for (int i = lane; i < T; i += 64) {
            int nxt = min(i + 1, T - 1);
            prop_p[b * T + i] = ff[nxt];
        }
    }
}

// ---------------------------------------------------------------------------
// Kernel 2: q/k/v projections. 256 threads = 4 waves; block handles 4 rows
// (one per wave); x rows staged in LDS; waves stream same W addrs -> L1 reuse.
// ---------------------------------------------------------------------------
__global__ __launch_bounds__(256) void qkv_kernel(const float* __restrict__ x,
                                                  const float* __restrict__ Wq,
                                                  const float* __restrict__ Wk,
                                                  const float* __restrict__ Wv,
                                                  float* __restrict__ q,
                                                  float* __restrict__ k,
                                                  float* __restrict__ v) {
    int r0 = blockIdx.x * 4;            // first row of 4
    int tid = threadIdx.x;
    int wave = tid >> 6;
    int c = tid & 63;

    __shared__ float xs[4 * C];
    const float4* xv4 = (const float4*)(x + (size_t)r0 * C);
    float4* xs4 = (float4*)xs;
#pragma unroll
    for (int i = 0; i < 2; ++i) xs4[tid + 256 * i] = xv4[tid + 256 * i];
    __syncthreads();

    const float* xr = xs + wave * C;
    float aq = 0.f, ak = 0.f, av = 0.f;
#pragma unroll 8
    for (int kk = 0; kk < C; ++kk) {
        float xv = xr[kk];
        aq = fmaf(xv, Wq[kk * H + c], aq);
        ak = fmaf(xv, Wk[kk * H + c], ak);
        av = fmaf(xv, Wv[kk * H + c], av);
    }
    size_t o = (size_t)(r0 + wave) * H + c;
    q[o] = aq;
    k[o] = ak;
    v[o] = av;
}

// ---------------------------------------------------------------------------
// Kernel 3: relative-embedding sums -> k' = scale*k + Rk, v' = v + Rv.
// 256 threads = 4 waves per (b,j); indices precomputed to LDS shorts;
// i-loop split across waves (128 each); LDS partial reduce.
// ---------------------------------------------------------------------------
__global__ __launch_bounds__(256) void relsum_kernel(
    const float* __restrict__ prop_t, const float* __restrict__ prop_p,
    const float* __restrict__ Ek_pos, const float* __restrict__ Ev_pos,
    const float* __restrict__ Ek_time, const float* __restrict__ Ev_time,
    const float* __restrict__ Ek_pitch, const float* __restrict__ Ev_pitch,
    float* __restrict__ k, float* __restrict__ v) {
    int b = blockIdx.x >> 9;
    int j = blockIdx.x & 511;
    int tid = threadIdx.x;
    int wave = tid >> 6;
    int c = tid & 63;

    __shared__ float pt[T];
    __shared__ float pp[T];
    __shared__ short tis[T];
    __shared__ short nis[T];
    __shared__ float redK[256];
    __shared__ float redV[256];

#pragma unroll
    for (int u = 0; u < 2; ++u) {
        int i = tid + u * 256;
        pt[i] = prop_t[b * T + i];
        pp[i] = prop_p[b * T + i];
    }
    __syncthreads();

    float pjt = pt[j];
    float pjp = pp[j];

#pragma unroll
    for (int u = 0; u < 2; ++u) {
        int i = tid + u * 256;
        float dt = pjt - pt[i];
        int ti;
        if (dt != dt) ti = 0;
        else ti = (int)fminf(fmaxf(dt, -200.f), 200.f) + 200;
        tis[i] = (short)ti;
        float dp = pjp - pp[i];
        int ni;
        if (dp != dp) ni = 0;
        else ni = (int)fminf(fmaxf(dp, -128.f), 128.f) + 128;
        nis[i] = (short)ni;
    }
    __syncthreads();

    float aK = 0.f, aV = 0.f;
    int i0 = wave * 128;
#pragma unroll 4
    for (int u = 0; u < 128; ++u) {
        int i = i0 + u;
        int pd = min(max(j - i, -25), 25) + 25;
        int ti = (int)tis[i];
        int ni = (int)nis[i];
        aK += Ek_pos[pd * H + c] + Ek_time[ti * H + c] + Ek_pitch[ni * H + c];
        aV += Ev_pos[pd * H + c] + Ev_time[ti * H + c] + Ev_pitch[ni * H + c];
    }

    redK[tid] = aK;
    redV[tid] = aV;
    __syncthreads();

    if (tid < 64) {
        float sK = redK[tid] + redK[64 + tid] + redK[128 + tid] + redK[192 + tid];
        float sV = redV[tid] + redV[64 + tid] + redV[128 + tid] + redV[192 + tid];
        size_t o = (size_t)blockIdx.x * H + tid;
        k[o] = SCALE * k[o] + sK;
        v[o] = v[o] + sV;
    }
}

// ---------------------------------------------------------------------------
// Kernel 4: causal attention. 256 threads = 4 waves per (b,t).
// Scores: coop-loaded 64-s k-tile, per-wave c-quarter partial dots + combine.
// Softmax: block reduce. PV: 4-way s-split + LDS reduce.
// ---------------------------------------------------------------------------
__global__ __launch_bounds__(256) void attn_kernel(const float* __restrict__ q,
                                                   const float* __restrict__ kp,
                                                   const float* __restrict__ vp,
                                                   float* __restrict__ out) {
    int b = blockIdx.x >> 9;
    int t = blockIdx.x & 511;
    int tid = threadIdx.x;
    int wave = tid >> 6;
    int lane = tid & 63;

    __shared__ float qs[H];
    __shared__ float sc[T];
    __shared__ float ktile[64 * 65];
    __shared__ float red[256];
    __shared__ float mred[4];
    __shared__ float sred[4];

    if (tid < H) qs[tid] = q[(size_t)blockIdx.x * H + tid];
    __syncthreads();

    int ns = t + 1;
    const float* kbase = kp + (size_t)b * T * H;
    const float* vbase = vp + (size_t)b * T * H;

    // ---- scores ----
    int c0 = wave * 16;
    for (int s0 = 0; s0 < ns; s0 += 64) {
        int tile = min(64, ns - s0);
        for (int f = tid; f < tile * 64; f += 256) {
            int r = f >> 6, cc = f & 63;
            ktile[r * 65 + cc] = kbase[(size_t)(s0 + r) * H + cc];
        }
        __syncthreads();
        float p = 0.f;
        if (lane < tile) {
#pragma unroll
            for (int i = 0; i < 16; ++i)
                p = fmaf(qs[c0 + i], ktile[lane * 65 + c0 + i], p);
        }
        red[wave * 64 + lane] = p;
        __syncthreads();
        if (tid < tile)
            sc[s0 + tid] = red[tid] + red[64 + tid] + red[128 + tid] + red[192 + tid];
        __syncthreads();
    }

    // ---- softmax ----
    float m = -INFINITY;
    for (int s = tid; s < ns; s += 256) m = fmaxf(m, sc[s]);
#pragma unroll
    for (int off = 32; off; off >>= 1) m = fmaxf(m, __shfl_down(m, off));
    if (lane == 0) mred[wave] = m;
    __syncthreads();
    m = fmaxf(fmaxf(mred[0], mred[1]), fmaxf(mred[2], mred[3]));

    float lsum = 0.f;
    for (int s = tid; s < ns; s += 256) {
        float e = __expf(sc[s] - m);
        sc[s] = e;
        lsum += e;
    }
#pragma unroll
    for (int off = 32; off; off >>= 1) lsum += __shfl_down(lsum, off);
    if (lane == 0) sred[wave] = lsum;
    __syncthreads();
    float sum = sred[0] + sred[1] + sred[2] + sred[3];

    // ---- PV ----
    float acc = 0.f;
#pragma unroll 4
    for (int s = wave; s < ns; s += 4)
        acc = fmaf(sc[s], vbase[(size_t)s * H + lane], acc);
    red[tid] = acc;
    __syncthreads();

    if (tid < 64) {
        float a = red[tid] + red[64 + tid] + red[128 + tid] + red[192 + tid];
        out[(size_t)blockIdx.x * H + tid] = a * (1.0f / sum);
    }
}

// ---------------------------------------------------------------------------
extern "C" void kernel_launch(void* const* d_in, const int* in_sizes, int n_in,
                              void* d_out, int out_size, void* d_ws, size_t ws_size,
                              hipStream_t stream) {
    const float* x        = (const float*)d_in[0];
    const int*   tok      = (const int*)d_in[1];
    const float* Wk       = (const float*)d_in[2];
    const float* Wq       = (const float*)d_in[3];
    const float* Wv       = (const float*)d_in[4];
    const float* Ek_pos   = (const float*)d_in[5];
    const float* Ev_pos   = (const float*)d_in[6];
    const float* Ek_time  = (const float*)d_in[7];
    const float* Ev_time  = (const float*)d_in[8];
    const float* Ek_pitch = (const float*)d_in[9];
    const float* Ev_pitch = (const float*)d_in[10];
    float* out = (float*)d_out;

    float* ws = (float*)d_ws;
    float* q      = ws;                       // B*T*H
    float* k      = q + B * T * H;            // B*T*H (becomes k')
    float* v      = k + B * T * H;            // B*T*H (becomes v')
    float* prop_t = v + B * T * H;            // B*T
    float* prop_p = prop_t + B * T;           // B*T

    scan_kernel<<<B, 64, 0, stream>>>(tok, prop_t, prop_p);
    qkv_kernel<<<B * T / 4, 256, 0, stream>>>(x, Wq, Wk, Wv, q, k, v);
    relsum_kernel<<<B * T, 256, 0, stream>>>(prop_t, prop_p, Ek_pos, Ev_pos,
                                             Ek_time, Ev_time, Ek_pitch, Ev_pitch,
                                             k, v);
    attn_kernel<<<B * T, 256, 0, stream>>>(q, k, v, out);
}